// Round 2
// baseline (294.924 us; speedup 1.0000x reference)
//
#include <hip/hip_runtime.h>
#include <hip/hip_bf16.h>

// DiffLogic: 3-layer differentiable logic network.
// Round 2: latency-bound fix. One wave = 4 gates, explicitly unrolled so all
// 8 gathers (2 per gate, 1 KB coalesced each) are in flight simultaneously.
// Wave-uniform idx/coef loads forced scalar via readfirstlane on wave id.

#define BATCH   256
#define IN_DIM  1024
#define WIDTH   64000
#define NGROUP  10
#define GSIZE   6400      // WIDTH / NGROUP
#define TAU     30.0f
#define GPW     4         // gates per wave (unrolled)
#define GPB     16        // gates per block = 4 waves * GPW ; 6400 % 16 == 0

// ---------------------------------------------------------------- transpose
// x:(256,1024) row-major -> xT:(1024,256)
__global__ __launch_bounds__(256) void transpose_kernel(
    const float* __restrict__ x, float* __restrict__ xT)
{
    __shared__ float tile[64][65];
    const int c0 = (blockIdx.x & 15) * 64;   // 1024/64 = 16 col tiles
    const int b0 = (blockIdx.x >> 4) * 64;   // 256/64  = 4 batch tiles
    const int lt = threadIdx.x & 63;
    const int wt = threadIdx.x >> 6;
    for (int r = wt; r < 64; r += 4)
        tile[r][lt] = x[(b0 + r) * IN_DIM + c0 + lt];        // coalesced read
    __syncthreads();
    for (int r = wt; r < 64; r += 4)
        xT[(c0 + r) * BATCH + b0 + lt] = tile[lt][r];        // coalesced write
}

// ---------------------------------------------------------------- coefficients
// coef[j] = softmax(w[j]) @ GATE_COEF, hard-coded dot products.
__global__ __launch_bounds__(256) void coef_kernel(
    const float* __restrict__ w1, const float* __restrict__ w2,
    const float* __restrict__ w3,
    float4* __restrict__ c1o, float4* __restrict__ c2o, float4* __restrict__ c3o)
{
    const int id = blockIdx.x * 256 + threadIdx.x;   // 0 .. 3*WIDTH-1
    const int layer = id / WIDTH;                    // wave-uniform (WIDTH%64==0)
    const int j = id - layer * WIDTH;
    const float* w = (layer == 0) ? w1 : (layer == 1) ? w2 : w3;
    float4* cc     = (layer == 0) ? c1o : (layer == 1) ? c2o : c3o;

    const float4* w4 = (const float4*)(w + (size_t)j * 16);
    float4 q0 = w4[0], q1 = w4[1], q2 = w4[2], q3 = w4[3];
    float p[16] = {q0.x,q0.y,q0.z,q0.w, q1.x,q1.y,q1.z,q1.w,
                   q2.x,q2.y,q2.z,q2.w, q3.x,q3.y,q3.z,q3.w};
    float m = p[0];
    #pragma unroll
    for (int i = 1; i < 16; ++i) m = fmaxf(m, p[i]);
    float s = 0.f;
    #pragma unroll
    for (int i = 0; i < 16; ++i) { p[i] = __expf(p[i] - m); s += p[i]; }
    const float inv = 1.0f / s;

    float c0 = (p[8]+p[9]+p[10]+p[11]+p[12]+p[13]+p[14]+p[15]) * inv;
    float c1 = (p[2]+p[3]+p[6]+p[7] - p[8]-p[9]-p[12]-p[13]) * inv;
    float c2 = (p[4]+p[5]+p[6]+p[7] - p[8]-p[9]-p[10]-p[11]) * inv;
    float c3 = (p[1]-p[2]-p[4]-2.f*p[6]-p[7]+p[8]+2.f*p[9]+p[11]+p[13]-p[14]) * inv;
    cc[j] = make_float4(c0, c1, c2, c3);
}

// ---------------------------------------------------------------- logic layer
// in : (in_width, 64) float4 columns (width-major, batch contiguous)
// out: (WIDTH, 64) float4            [if !FINAL]
// red_out: (BATCH, NGROUP) float, atomically accumulated, scaled 1/TAU [FINAL]
template<bool FINAL>
__global__ __launch_bounds__(256) void logic_layer_kernel(
    const float4* __restrict__ in,
    const float4* __restrict__ coefs,
    const int*    __restrict__ ia,
    const int*    __restrict__ ib,
    float4*       __restrict__ out,
    float*        __restrict__ red_out)
{
    const int lane = threadIdx.x & 63;
    const int wave = __builtin_amdgcn_readfirstlane(threadIdx.x >> 6);
    const int jw = blockIdx.x * GPB + wave * GPW;    // wave's first gate

    // Stage 1: wave-uniform metadata loads (scalar path), all independent.
    int    av[GPW], bv[GPW];
    float4 cv[GPW];
    #pragma unroll
    for (int u = 0; u < GPW; ++u) {
        av[u] = ia[jw + u];
        bv[u] = ib[jw + u];
        cv[u] = coefs[jw + u];
    }

    // Stage 2: all 2*GPW gathers issued back-to-back (8 outstanding 1 KB reads).
    float4 A[GPW], B[GPW];
    #pragma unroll
    for (int u = 0; u < GPW; ++u) {
        A[u] = in[(size_t)av[u] * 64 + lane];
        B[u] = in[(size_t)bv[u] * 64 + lane];
    }

    // Stage 3: compute + store / accumulate.
    float4 acc = make_float4(0.f, 0.f, 0.f, 0.f);
    #pragma unroll
    for (int u = 0; u < GPW; ++u) {
        const float4 c = cv[u];
        float4 r;
        r.x = fmaf(c.w, A[u].x * B[u].x, fmaf(c.z, B[u].x, fmaf(c.y, A[u].x, c.x)));
        r.y = fmaf(c.w, A[u].y * B[u].y, fmaf(c.z, B[u].y, fmaf(c.y, A[u].y, c.x)));
        r.z = fmaf(c.w, A[u].z * B[u].z, fmaf(c.z, B[u].z, fmaf(c.y, A[u].z, c.x)));
        r.w = fmaf(c.w, A[u].w * B[u].w, fmaf(c.z, B[u].w, fmaf(c.y, A[u].w, c.x)));
        if (FINAL) {
            acc.x += r.x; acc.y += r.y; acc.z += r.z; acc.w += r.w;
        } else {
            out[(size_t)(jw + u) * 64 + lane] = r;
        }
    }

    if (FINAL) {
        __shared__ float4 s[4][64];
        s[wave][lane] = acc;
        __syncthreads();
        if (wave == 0) {
            float4 t0 = s[0][lane], t1 = s[1][lane], t2 = s[2][lane], t3 = s[3][lane];
            const float sc = 1.0f / TAU;
            const int grp = (blockIdx.x * GPB) / GSIZE;   // block within one group
            const int b0 = lane * 4;
            atomicAdd(&red_out[(b0 + 0) * NGROUP + grp], (t0.x + t1.x + t2.x + t3.x) * sc);
            atomicAdd(&red_out[(b0 + 1) * NGROUP + grp], (t0.y + t1.y + t2.y + t3.y) * sc);
            atomicAdd(&red_out[(b0 + 2) * NGROUP + grp], (t0.z + t1.z + t2.z + t3.z) * sc);
            atomicAdd(&red_out[(b0 + 3) * NGROUP + grp], (t0.w + t1.w + t2.w + t3.w) * sc);
        }
    }
}

// ---------------------------------------------------------------- launch
extern "C" void kernel_launch(void* const* d_in, const int* in_sizes, int n_in,
                              void* d_out, int out_size, void* d_ws, size_t ws_size,
                              hipStream_t stream)
{
    const float* x   = (const float*)d_in[0];
    const float* w1  = (const float*)d_in[1];
    const float* w2  = (const float*)d_in[2];
    const float* w3  = (const float*)d_in[3];
    const int*   ia1 = (const int*)d_in[4];
    const int*   ib1 = (const int*)d_in[5];
    const int*   ia2 = (const int*)d_in[6];
    const int*   ib2 = (const int*)d_in[7];
    const int*   ia3 = (const int*)d_in[8];
    const int*   ib3 = (const int*)d_in[9];
    float* out = (float*)d_out;

    // workspace layout (floats): xT | h1 | h2 | c1 | c2 | c3  ~= 135 MB
    float* ws = (float*)d_ws;
    float* xT = ws;
    float* h1 = xT + (size_t)IN_DIM * BATCH;        // 262144
    float* h2 = h1 + (size_t)WIDTH * BATCH;         // +16384000
    float* c1 = h2 + (size_t)WIDTH * BATCH;         // +16384000
    float* c2 = c1 + (size_t)WIDTH * 4;
    float* c3 = c2 + (size_t)WIDTH * 4;

    hipMemsetAsync(d_out, 0, (size_t)out_size * sizeof(float), stream);

    transpose_kernel<<<64, 256, 0, stream>>>(x, xT);
    coef_kernel<<<(3 * WIDTH) / 256, 256, 0, stream>>>(w1, w2, w3,
                                                       (float4*)c1, (float4*)c2, (float4*)c3);

    logic_layer_kernel<false><<<WIDTH / GPB, 256, 0, stream>>>(
        (const float4*)xT, (const float4*)c1, ia1, ib1, (float4*)h1, nullptr);
    logic_layer_kernel<false><<<WIDTH / GPB, 256, 0, stream>>>(
        (const float4*)h1, (const float4*)c2, ia2, ib2, (float4*)h2, nullptr);
    logic_layer_kernel<true><<<WIDTH / GPB, 256, 0, stream>>>(
        (const float4*)h2, (const float4*)c3, ia3, ib3, nullptr, out);
}

// Round 3
// 183.170 us; speedup vs baseline: 1.6101x; 1.6101x over previous
//
#include <hip/hip_runtime.h>
#include <hip/hip_bf16.h>

// DiffLogic: 3-layer differentiable logic network.
// Round 3: R1 structure (1000 blocks, 16 gates/wave) + explicit register
// double-buffered gather pipeline: chunk k+1's 8x1KB gathers are issued
// before chunk k's computes, so ~8 loads/wave stay in flight.
// Check: VGPR_Count must be ~90+ or the compiler defeated the pipeline.

#define BATCH   256
#define IN_DIM  1024
#define WIDTH   64000
#define NGROUP  10
#define GSIZE   6400      // WIDTH / NGROUP
#define TAU     30.0f
#define GPW     16        // gates per wave (contiguous range)
#define CH      4         // gates per pipeline chunk (8 gathers in flight)
#define NCH     (GPW/CH)
#define GPB     64        // 4 waves * GPW ; 6400 % 64 == 0

// ---------------------------------------------------------------- transpose
// x:(256,1024) row-major -> xT:(1024,256)
__global__ __launch_bounds__(256) void transpose_kernel(
    const float* __restrict__ x, float* __restrict__ xT)
{
    __shared__ float tile[64][65];
    const int c0 = (blockIdx.x & 15) * 64;
    const int b0 = (blockIdx.x >> 4) * 64;
    const int lt = threadIdx.x & 63;
    const int wt = threadIdx.x >> 6;
    for (int r = wt; r < 64; r += 4)
        tile[r][lt] = x[(b0 + r) * IN_DIM + c0 + lt];
    __syncthreads();
    for (int r = wt; r < 64; r += 4)
        xT[(c0 + r) * BATCH + b0 + lt] = tile[lt][r];
}

// ---------------------------------------------------------------- coefficients
__global__ __launch_bounds__(256) void coef_kernel(
    const float* __restrict__ w1, const float* __restrict__ w2,
    const float* __restrict__ w3,
    float4* __restrict__ c1o, float4* __restrict__ c2o, float4* __restrict__ c3o)
{
    const int id = blockIdx.x * 256 + threadIdx.x;
    const int layer = id / WIDTH;
    const int j = id - layer * WIDTH;
    const float* w = (layer == 0) ? w1 : (layer == 1) ? w2 : w3;
    float4* cc     = (layer == 0) ? c1o : (layer == 1) ? c2o : c3o;

    const float4* w4 = (const float4*)(w + (size_t)j * 16);
    float4 q0 = w4[0], q1 = w4[1], q2 = w4[2], q3 = w4[3];
    float p[16] = {q0.x,q0.y,q0.z,q0.w, q1.x,q1.y,q1.z,q1.w,
                   q2.x,q2.y,q2.z,q2.w, q3.x,q3.y,q3.z,q3.w};
    float m = p[0];
    #pragma unroll
    for (int i = 1; i < 16; ++i) m = fmaxf(m, p[i]);
    float s = 0.f;
    #pragma unroll
    for (int i = 0; i < 16; ++i) { p[i] = __expf(p[i] - m); s += p[i]; }
    const float inv = 1.0f / s;

    float c0 = (p[8]+p[9]+p[10]+p[11]+p[12]+p[13]+p[14]+p[15]) * inv;
    float c1 = (p[2]+p[3]+p[6]+p[7] - p[8]-p[9]-p[12]-p[13]) * inv;
    float c2 = (p[4]+p[5]+p[6]+p[7] - p[8]-p[9]-p[10]-p[11]) * inv;
    float c3 = (p[1]-p[2]-p[4]-2.f*p[6]-p[7]+p[8]+2.f*p[9]+p[11]+p[13]-p[14]) * inv;
    cc[j] = make_float4(c0, c1, c2, c3);
}

// ---------------------------------------------------------------- logic layer
// in : (in_width, 64) float4 columns (width-major, batch contiguous)
template<bool FINAL>
__global__ __launch_bounds__(256) void logic_layer_kernel(
    const float4* __restrict__ in,
    const float4* __restrict__ coefs,
    const int*    __restrict__ ia,
    const int*    __restrict__ ib,
    float4*       __restrict__ out,
    float*        __restrict__ red_out)
{
    const int lane = threadIdx.x & 63;
    const int wave = __builtin_amdgcn_readfirstlane(threadIdx.x >> 6);
    const int jw = blockIdx.x * GPB + wave * GPW;   // contiguous 16-gate range

    // All metadata upfront: wave-uniform -> scalar loads (contiguous 64B runs).
    int av[GPW], bv[GPW];
    #pragma unroll
    for (int u = 0; u < GPW; ++u) { av[u] = ia[jw + u]; bv[u] = ib[jw + u]; }

    float4 Abuf[2][CH], Bbuf[2][CH], Cbuf[2][CH];

    // Prologue: chunk 0 gathers in flight.
    #pragma unroll
    for (int t = 0; t < CH; ++t) {
        Abuf[0][t] = in[(size_t)av[t] * 64 + lane];
        Bbuf[0][t] = in[(size_t)bv[t] * 64 + lane];
        Cbuf[0][t] = coefs[jw + t];
    }

    float4 acc = make_float4(0.f, 0.f, 0.f, 0.f);

    #pragma unroll
    for (int k = 0; k < NCH; ++k) {
        const int cur = k & 1, nxt = cur ^ 1;
        if (k + 1 < NCH) {
            #pragma unroll
            for (int t = 0; t < CH; ++t) {
                const int u = (k + 1) * CH + t;
                Abuf[nxt][t] = in[(size_t)av[u] * 64 + lane];
                Bbuf[nxt][t] = in[(size_t)bv[u] * 64 + lane];
                Cbuf[nxt][t] = coefs[jw + u];
            }
        }
        #pragma unroll
        for (int t = 0; t < CH; ++t) {
            const float4 c = Cbuf[cur][t];
            const float4 A = Abuf[cur][t];
            const float4 B = Bbuf[cur][t];
            float4 r;
            r.x = fmaf(c.w, A.x * B.x, fmaf(c.z, B.x, fmaf(c.y, A.x, c.x)));
            r.y = fmaf(c.w, A.y * B.y, fmaf(c.z, B.y, fmaf(c.y, A.y, c.x)));
            r.z = fmaf(c.w, A.z * B.z, fmaf(c.z, B.z, fmaf(c.y, A.z, c.x)));
            r.w = fmaf(c.w, A.w * B.w, fmaf(c.z, B.w, fmaf(c.y, A.w, c.x)));
            if (FINAL) {
                acc.x += r.x; acc.y += r.y; acc.z += r.z; acc.w += r.w;
            } else {
                out[(size_t)(jw + k * CH + t) * 64 + lane] = r;
            }
        }
    }

    if (FINAL) {
        __shared__ float4 s[4][64];
        s[wave][lane] = acc;
        __syncthreads();
        if (wave == 0) {
            float4 t0 = s[0][lane], t1 = s[1][lane], t2 = s[2][lane], t3 = s[3][lane];
            const float sc = 1.0f / TAU;
            const int grp = (blockIdx.x * GPB) / GSIZE;   // block within one group
            const int b0 = lane * 4;
            atomicAdd(&red_out[(b0 + 0) * NGROUP + grp], (t0.x + t1.x + t2.x + t3.x) * sc);
            atomicAdd(&red_out[(b0 + 1) * NGROUP + grp], (t0.y + t1.y + t2.y + t3.y) * sc);
            atomicAdd(&red_out[(b0 + 2) * NGROUP + grp], (t0.z + t1.z + t2.z + t3.z) * sc);
            atomicAdd(&red_out[(b0 + 3) * NGROUP + grp], (t0.w + t1.w + t2.w + t3.w) * sc);
        }
    }
}

// ---------------------------------------------------------------- launch
extern "C" void kernel_launch(void* const* d_in, const int* in_sizes, int n_in,
                              void* d_out, int out_size, void* d_ws, size_t ws_size,
                              hipStream_t stream)
{
    const float* x   = (const float*)d_in[0];
    const float* w1  = (const float*)d_in[1];
    const float* w2  = (const float*)d_in[2];
    const float* w3  = (const float*)d_in[3];
    const int*   ia1 = (const int*)d_in[4];
    const int*   ib1 = (const int*)d_in[5];
    const int*   ia2 = (const int*)d_in[6];
    const int*   ib2 = (const int*)d_in[7];
    const int*   ia3 = (const int*)d_in[8];
    const int*   ib3 = (const int*)d_in[9];
    float* out = (float*)d_out;

    // workspace layout (floats): xT | h1 | h2 | c1 | c2 | c3  ~= 135 MB
    float* ws = (float*)d_ws;
    float* xT = ws;
    float* h1 = xT + (size_t)IN_DIM * BATCH;
    float* h2 = h1 + (size_t)WIDTH * BATCH;
    float* c1 = h2 + (size_t)WIDTH * BATCH;
    float* c2 = c1 + (size_t)WIDTH * 4;
    float* c3 = c2 + (size_t)WIDTH * 4;

    hipMemsetAsync(d_out, 0, (size_t)out_size * sizeof(float), stream);

    transpose_kernel<<<64, 256, 0, stream>>>(x, xT);
    coef_kernel<<<(3 * WIDTH) / 256, 256, 0, stream>>>(w1, w2, w3,
                                                       (float4*)c1, (float4*)c2, (float4*)c3);

    logic_layer_kernel<false><<<WIDTH / GPB, 256, 0, stream>>>(
        (const float4*)xT, (const float4*)c1, ia1, ib1, (float4*)h1, nullptr);
    logic_layer_kernel<false><<<WIDTH / GPB, 256, 0, stream>>>(
        (const float4*)h1, (const float4*)c2, ia2, ib2, (float4*)h2, nullptr);
    logic_layer_kernel<true><<<WIDTH / GPB, 256, 0, stream>>>(
        (const float4*)h2, (const float4*)c3, ia3, ib3, nullptr, out);
}